// Round 8
// baseline (13013.597 us; speedup 1.0000x reference)
//
#include <hip/hip_runtime.h>
#include <hip/hip_bf16.h>

#define KD 4096
#define ND 11008
#define MD 16384
#define KGD 32
#define NTT (KD / 32)

typedef __hip_bfloat16 bf16;
typedef float f32x4 __attribute__((ext_vector_type(4)));
typedef short bf16x8 __attribute__((ext_vector_type(8)));

#define WAITV(n) asm volatile("s_waitcnt vmcnt(" #n ")" ::: "memory")
#define BAR()    asm volatile("s_barrier" ::: "memory")

__device__ __forceinline__ void gload16(const bf16* g, bf16* l) {
    __builtin_amdgcn_global_load_lds((const __attribute__((address_space(1))) void*)g,
                                     (__attribute__((address_space(3))) void*)l, 16, 0, 0);
}

// ---------------------------------------------------------------------------
// x: fp32 -> bf16 (8 elems/thread)
// ---------------------------------------------------------------------------
__global__ void cvt_kernel(const float* __restrict__ x, bf16* __restrict__ y, int n8) {
    int i = blockIdx.x * blockDim.x + threadIdx.x;
    if (i >= n8) return;
    const f32x4* p = reinterpret_cast<const f32x4*>(x + (size_t)i * 8);
    f32x4 a = p[0], b = p[1];
    bf16 o[8];
#pragma unroll
    for (int e = 0; e < 4; ++e) {
        o[e]     = __float2bfloat16(a[e]);
        o[4 + e] = __float2bfloat16(b[e]);
    }
    *reinterpret_cast<bf16x8*>(y + (size_t)i * 8) = *reinterpret_cast<bf16x8*>(o);
}

// ---------------------------------------------------------------------------
// dequant packed int4 -> bf16 rows [n0 .. n0+rows) into wd (chunk-local)
// ---------------------------------------------------------------------------
__global__ void dequant_kernel(const int* __restrict__ wp, const float* __restrict__ sc,
                               bf16* __restrict__ wd, int n0, int rows) {
    const int per_row = KD / 8;
    int t = blockIdx.x * blockDim.x + threadIdx.x;
    if (t >= rows * per_row) return;
    int lr = t / per_row;
    int q  = t - lr * per_row;
    int n  = n0 + lr;
    int j  = q * 4;
    const int4 p = *reinterpret_cast<const int4*>(wp + (size_t)n * (KD / 2) + j);
    float s = sc[(size_t)n * KGD + (j >> 6)];
    int v[4] = {p.x, p.y, p.z, p.w};
    bf16 o[8];
#pragma unroll
    for (int i = 0; i < 4; ++i) {
        o[2 * i]     = __float2bfloat16((float)((v[i] & 0xF) - 8) * s);
        o[2 * i + 1] = __float2bfloat16((float)(((v[i] >> 4) & 0xF) - 8) * s);
    }
    *reinterpret_cast<bf16x8*>(wd + (size_t)lr * KD + j * 2) = *reinterpret_cast<bf16x8*>(o);
}

// ---------------------------------------------------------------------------
// GEMM: C[M,N] = A[M,K] * B[N,K]^T, bf16 in, fp32 out.
// 256x256 tile, BK=32, 512 thr / 8 waves (2M x 4N), per-wave out 128x64,
// mfma_f32_16x16x32_bf16. LDS [2buf][A/B][256x32] = 64 KiB -> 2 blocks/CU
// (16 waves/CU): co-resident blocks overlap MFMA and LDS/stage phases
// (m114 mechanism) instead of relying on intra-block scheduling.
// Proven 16-row chunk swizzle (0 conflicts), pre-swizzled global source.
// Race-free ledger: stage(t+1) -> WAITV(4) (tile t landed) -> BAR ->
// compute(t) -> BAR (closes WAR window before next stage overwrites).
// ---------------------------------------------------------------------------
__global__ __launch_bounds__(512, 4) void gemm256(const bf16* __restrict__ A,
                                                  const bf16* __restrict__ B,
                                                  float* __restrict__ C,
                                                  int mtiles, int ntiles, int n0base) {
    __shared__ bf16 lds[2][2][8192];  // [buf][op(A/B)][256 rows x 32 k, swizzled]
    const int tid  = threadIdx.x;
    const int lane = tid & 63;
    const int w    = tid >> 6;

    // bijective XCD-aware block swizzle (n fastest: consecutive share A-panel)
    int nwg = mtiles * ntiles;
    int orig = blockIdx.x;
    int q8 = nwg >> 3, r8 = nwg & 7;
    int xcd = orig & 7, off = orig >> 3;
    int wg = (xcd < r8 ? xcd * (q8 + 1) : r8 * (q8 + 1) + (xcd - r8) * q8) + off;
    const int mb = wg / ntiles, nb = wg - mb * ntiles;
    const int m0 = mb * 256, n0 = nb * 256;

    const int wm = w >> 2, wn = w & 3;
    const int rl = lane & 15, kq = lane >> 4;
    const int sz = (rl >> 1) & 3;
    const int ro = 8 * (kq ^ sz);          // swizzled k-chunk for ds_read

    // staging source (pre-swizzled so linear gload_lds dest == swizzled layout)
    const int src_c = (((lane & 3) ^ ((lane >> 3) & 3)) << 3);
    const int src_r = (w << 4) + (lane >> 2);          // 8 waves x 16 rows = 128
    const bf16* Abase = A + (size_t)(m0 + src_r) * KD + src_c;
    const bf16* Bbase = B + (size_t)(n0 + src_r) * KD + src_c;

    f32x4 acc[8][4] = {};

    auto stage = [&](int b, int k0) {
        const bf16* ga = Abase + k0;
        const bf16* gb = Bbase + k0;
        bf16* la = &lds[b][0][w * 512];
        bf16* lb = &lds[b][1][w * 512];
        gload16(ga, la);
        gload16(ga + (size_t)128 * KD, la + 4096);     // rows +128
        gload16(gb, lb);
        gload16(gb + (size_t)128 * KD, lb + 4096);
    };

    auto compute = [&](int b) {
        bf16x8 af[8], bfr[4];
#pragma unroll
        for (int mi = 0; mi < 8; ++mi)
            af[mi] = *reinterpret_cast<const bf16x8*>(
                &lds[b][0][(wm * 128 + mi * 16 + rl) * 32 + ro]);
#pragma unroll
        for (int ni = 0; ni < 4; ++ni)
            bfr[ni] = *reinterpret_cast<const bf16x8*>(
                &lds[b][1][(wn * 64 + ni * 16 + rl) * 32 + ro]);
        __builtin_amdgcn_s_setprio(1);
#pragma unroll
        for (int mi = 0; mi < 8; ++mi)
#pragma unroll
            for (int ni = 0; ni < 4; ++ni)
                acc[mi][ni] = __builtin_amdgcn_mfma_f32_16x16x32_bf16(
                    af[mi], bfr[ni], acc[mi][ni], 0, 0, 0);
        __builtin_amdgcn_s_setprio(0);
    };

    // prologue: tile 0 -> buf 0 (4 loads outstanding)
    stage(0, 0);

    for (int t = 0; t < NTT - 1; ++t) {
        stage((t + 1) & 1, (t + 1) * 32);   // +4 -> 8 outstanding (buf free: BAR below)
        WAITV(4);                           // own tile-t loads landed
        BAR();                              // => all waves' tile-t data landed
        compute(t & 1);
        BAR();                              // all reads of buf[t&1] done -> WAR-safe
    }
    WAITV(0);
    BAR();
    compute((NTT - 1) & 1);

    // epilogue: C/D layout col=lane&15, row=(lane>>4)*4+r ; fp32 out
    const int crow = m0 + wm * 128 + kq * 4;
    const int ccol = n0base + n0 + wn * 64 + rl;
#pragma unroll
    for (int mi = 0; mi < 8; ++mi) {
#pragma unroll
        for (int r = 0; r < 4; ++r) {
            float* cp = C + (size_t)(crow + mi * 16 + r) * ND + ccol;
#pragma unroll
            for (int ni = 0; ni < 4; ++ni)
                cp[ni * 16] = acc[mi][ni][r];
        }
    }
}

extern "C" void kernel_launch(void* const* d_in, const int* in_sizes, int n_in,
                              void* d_out, int out_size, void* d_ws, size_t ws_size,
                              hipStream_t stream) {
    const float* x  = (const float*)d_in[0];
    const int*   wp = (const int*)d_in[1];
    const float* sc = (const float*)d_in[2];
    float* out = (float*)d_out;

    // partition ws into x-bf16 chunk (mc rows) + W-bf16 chunk (nc rows), both x256
    long long rows_cap = (long long)(ws_size / ((size_t)KD * 2));
    int mc, nc;
    if (rows_cap >= MD + 256) {
        mc = MD;
        long long r = rows_cap - MD;
        nc = (int)((r / 256) * 256);
        if (nc > ND) nc = ND;
    } else if (rows_cap >= ND + 256) {
        nc = ND;
        long long r = rows_cap - ND;
        mc = (int)((r / 256) * 256);
        if (mc > MD) mc = MD;
    } else {
        nc = (int)(((rows_cap / 2) / 256) * 256);
        if (nc > ND) nc = ND;
        long long r = rows_cap - nc;
        mc = (int)((r / 256) * 256);
        if (mc > MD) mc = MD;
        if (mc <= 0 || nc <= 0) return;
    }

    bf16* xbuf = (bf16*)d_ws;
    bf16* wbuf = xbuf + (size_t)mc * KD;

    for (int m0 = 0; m0 < MD; m0 += mc) {
        int mrows = (MD - m0 < mc) ? (MD - m0) : mc;   // multiple of 256
        int n8 = mrows * (KD / 8);
        cvt_kernel<<<(n8 + 255) / 256, 256, 0, stream>>>(x + (size_t)m0 * KD, xbuf, n8);
        for (int n0 = 0; n0 < ND; n0 += nc) {
            int nrows = (ND - n0 < nc) ? (ND - n0) : nc;  // multiple of 256
            int tt = nrows * (KD / 8);
            dequant_kernel<<<(tt + 255) / 256, 256, 0, stream>>>(wp, sc, wbuf, n0, nrows);
            int mt = mrows / 256, nt2 = nrows / 256;
            gemm256<<<mt * nt2, 512, 0, stream>>>(xbuf, wbuf, out + (size_t)m0 * ND, mt, nt2, n0);
        }
    }
}

// Round 9
// 1656.748 us; speedup vs baseline: 7.8549x; 7.8549x over previous
//
#include <hip/hip_runtime.h>
#include <hip/hip_bf16.h>

#define KD 4096
#define ND 11008
#define MD 16384
#define KGD 32
#define NT (KD / 64)

typedef __hip_bfloat16 bf16;
typedef float f32x4 __attribute__((ext_vector_type(4)));
typedef short bf16x8 __attribute__((ext_vector_type(8)));

#define WAITV(n) asm volatile("s_waitcnt vmcnt(" #n ")" ::: "memory")
#define BAR()    asm volatile("s_barrier" ::: "memory")
#define SB()     __builtin_amdgcn_sched_barrier(0)

__device__ __forceinline__ void gload16(const bf16* g, bf16* l) {
    __builtin_amdgcn_global_load_lds((const __attribute__((address_space(1))) void*)g,
                                     (__attribute__((address_space(3))) void*)l, 16, 0, 0);
}

// ---------------------------------------------------------------------------
// x: fp32 -> bf16 (8 elems/thread)
// ---------------------------------------------------------------------------
__global__ void cvt_kernel(const float* __restrict__ x, bf16* __restrict__ y, int n8) {
    int i = blockIdx.x * blockDim.x + threadIdx.x;
    if (i >= n8) return;
    const f32x4* p = reinterpret_cast<const f32x4*>(x + (size_t)i * 8);
    f32x4 a = p[0], b = p[1];
    bf16 o[8];
#pragma unroll
    for (int e = 0; e < 4; ++e) {
        o[e]     = __float2bfloat16(a[e]);
        o[4 + e] = __float2bfloat16(b[e]);
    }
    *reinterpret_cast<bf16x8*>(y + (size_t)i * 8) = *reinterpret_cast<bf16x8*>(o);
}

// ---------------------------------------------------------------------------
// dequant packed int4 -> bf16 rows [n0 .. n0+rows) into wd (chunk-local)
// ---------------------------------------------------------------------------
__global__ void dequant_kernel(const int* __restrict__ wp, const float* __restrict__ sc,
                               bf16* __restrict__ wd, int n0, int rows) {
    const int per_row = KD / 8;
    int t = blockIdx.x * blockDim.x + threadIdx.x;
    if (t >= rows * per_row) return;
    int lr = t / per_row;
    int q  = t - lr * per_row;
    int n  = n0 + lr;
    int j  = q * 4;
    const int4 p = *reinterpret_cast<const int4*>(wp + (size_t)n * (KD / 2) + j);
    float s = sc[(size_t)n * KGD + (j >> 6)];
    int v[4] = {p.x, p.y, p.z, p.w};
    bf16 o[8];
#pragma unroll
    for (int i = 0; i < 4; ++i) {
        o[2 * i]     = __float2bfloat16((float)((v[i] & 0xF) - 8) * s);
        o[2 * i + 1] = __float2bfloat16((float)(((v[i] >> 4) & 0xF) - 8) * s);
    }
    *reinterpret_cast<bf16x8*>(wd + (size_t)lr * KD + j * 2) = *reinterpret_cast<bf16x8*>(o);
}

// ---------------------------------------------------------------------------
// GEMM: C[M,N] = A[M,K] * B[N,K]^T, bf16 in, fp32 out.
// 256x256 tile, BK=64 (two kh=32 halves), 512 thr / 8 waves (2M x 4N),
// per-wave out 128x64, mfma_f32_16x16x32_bf16. LDS 128 KiB double-buffered,
// proven chunk swizzle (0 conflicts) via pre-swizzled global source.
// Anti-lockstep compute: per kh, quadrant-pinned order
//   {read af(8)+b01(2) | read b23(2) | MFMA af*b01 (16) | MFMA af*b23 (16)}
// with sched_barrier(0) pins -> compiler's fine auto-lgkmcnt waits only on
// the oldest 10 reads for q0; per-wave kh1 read bursts drift under other
// waves' MFMA windows. Same 12 b128 frag regs as R4/R5 (no occupancy risk).
// Ledger: stage(t+1) -> WAITV(8) (tile t landed) -> BAR -> compute(t) -> BAR
// (closes WAR window before tile t+2's stage can land in buf[t&1^1]).
// ---------------------------------------------------------------------------
__global__ __launch_bounds__(512, 2) void gemm256(const bf16* __restrict__ A,
                                                  const bf16* __restrict__ B,
                                                  float* __restrict__ C,
                                                  int mtiles, int ntiles, int n0base) {
    __shared__ bf16 lds[2][2][2][8192];  // [buf][kh][op(A/B)][256 rows x 32 k, swizzled]
    const int tid  = threadIdx.x;
    const int lane = tid & 63;
    const int w    = tid >> 6;

    // bijective XCD-aware block swizzle
    int nwg = mtiles * ntiles;
    int orig = blockIdx.x;
    int q8 = nwg >> 3, r8 = nwg & 7;
    int xcd = orig & 7, off = orig >> 3;
    int wg = (xcd < r8 ? xcd * (q8 + 1) : r8 * (q8 + 1) + (xcd - r8) * q8) + off;
    const int mb = wg / ntiles, nb = wg - mb * ntiles;
    const int m0 = mb * 256, n0 = nb * 256;

    const int wm = w >> 2, wn = w & 3;
    const int rl = lane & 15, kq = lane >> 4;
    const int sz = (rl >> 1) & 3;
    const int ro = 8 * (kq ^ sz);          // swizzled k-chunk for ds_read

    // staging source (pre-swizzled so linear gload_lds dest == swizzled layout)
    const int src_c = (((lane & 3) ^ ((lane >> 3) & 3)) << 3);
    const int src_r = (w << 4) + (lane >> 2);
    const bf16* Abase = A + (size_t)(m0 + src_r) * KD + src_c;
    const bf16* Bbase = B + (size_t)(n0 + src_r) * KD + src_c;

    f32x4 acc[8][4] = {};

    auto stage = [&](int b, int kh, int k0) {
        const bf16* ga = Abase + k0 + kh * 32;
        const bf16* gb = Bbase + k0 + kh * 32;
        bf16* la = &lds[b][kh][0][w * 512];
        bf16* lb = &lds[b][kh][1][w * 512];
        gload16(ga, la);
        gload16(ga + (size_t)128 * KD, la + 4096);
        gload16(gb, lb);
        gload16(gb + (size_t)128 * KD, lb + 4096);
    };

    auto compute = [&](int b) {
        bf16x8 af[8], b01[2], b23[2];
#pragma unroll
        for (int kh = 0; kh < 2; ++kh) {
            const bf16* ua = &lds[b][kh][0][0];
            const bf16* ub = &lds[b][kh][1][0];
#pragma unroll
            for (int mi = 0; mi < 8; ++mi)
                af[mi] = *reinterpret_cast<const bf16x8*>(
                    &ua[(wm * 128 + mi * 16 + rl) * 32 + ro]);
#pragma unroll
            for (int ni = 0; ni < 2; ++ni)
                b01[ni] = *reinterpret_cast<const bf16x8*>(
                    &ub[(wn * 64 + ni * 16 + rl) * 32 + ro]);
            SB();   // af+b01 are the oldest 10 reads
#pragma unroll
            for (int ni = 0; ni < 2; ++ni)
                b23[ni] = *reinterpret_cast<const bf16x8*>(
                    &ub[(wn * 64 + (2 + ni) * 16 + rl) * 32 + ro]);
            SB();   // q0 below depends only on af+b01 -> auto lgkmcnt leaves b23 in flight
            __builtin_amdgcn_s_setprio(1);
#pragma unroll
            for (int mi = 0; mi < 8; ++mi)
#pragma unroll
                for (int ni = 0; ni < 2; ++ni)
                    acc[mi][ni] = __builtin_amdgcn_mfma_f32_16x16x32_bf16(
                        af[mi], b01[ni], acc[mi][ni], 0, 0, 0);
            __builtin_amdgcn_s_setprio(0);
            SB();
            __builtin_amdgcn_s_setprio(1);
#pragma unroll
            for (int mi = 0; mi < 8; ++mi)
#pragma unroll
                for (int ni = 0; ni < 2; ++ni)
                    acc[mi][2 + ni] = __builtin_amdgcn_mfma_f32_16x16x32_bf16(
                        af[mi], b23[ni], acc[mi][2 + ni], 0, 0, 0);
            __builtin_amdgcn_s_setprio(0);
            SB();
        }
    };

    // prologue: tile 0 -> buf 0 (8 loads outstanding)
    stage(0, 0, 0);
    stage(0, 1, 0);

    for (int t = 0; t < NT - 1; ++t) {
        const int cur = t & 1, nxt = cur ^ 1, k0n = (t + 1) * 64;
        stage(nxt, 0, k0n);
        stage(nxt, 1, k0n);     // 16 outstanding
        WAITV(8);               // tile t fully landed
        BAR();                  // all waves: tile t visible
        compute(cur);
        BAR();                  // all reads of buf[cur] done -> WAR-safe for t+2 stage
    }
    WAITV(0);
    BAR();
    compute((NT - 1) & 1);

    // epilogue: C/D layout col=lane&15, row=(lane>>4)*4+r ; fp32 out
    const int crow = m0 + wm * 128 + kq * 4;
    const int ccol = n0base + n0 + wn * 64 + rl;
#pragma unroll
    for (int mi = 0; mi < 8; ++mi) {
#pragma unroll
        for (int r = 0; r < 4; ++r) {
            float* cp = C + (size_t)(crow + mi * 16 + r) * ND + ccol;
#pragma unroll
            for (int ni = 0; ni < 4; ++ni)
                cp[ni * 16] = acc[mi][ni][r];
        }
    }
}

extern "C" void kernel_launch(void* const* d_in, const int* in_sizes, int n_in,
                              void* d_out, int out_size, void* d_ws, size_t ws_size,
                              hipStream_t stream) {
    const float* x  = (const float*)d_in[0];
    const int*   wp = (const int*)d_in[1];
    const float* sc = (const float*)d_in[2];
    float* out = (float*)d_out;

    // partition ws into x-bf16 chunk (mc rows) + W-bf16 chunk (nc rows), both x256
    long long rows_cap = (long long)(ws_size / ((size_t)KD * 2));
    int mc, nc;
    if (rows_cap >= MD + 256) {
        mc = MD;
        long long r = rows_cap - MD;
        nc = (int)((r / 256) * 256);
        if (nc > ND) nc = ND;
    } else if (rows_cap >= ND + 256) {
        nc = ND;
        long long r = rows_cap - ND;
        mc = (int)((r / 256) * 256);
        if (mc > MD) mc = MD;
    } else {
        nc = (int)(((rows_cap / 2) / 256) * 256);
        if (nc > ND) nc = ND;
        long long r = rows_cap - nc;
        mc = (int)((r / 256) * 256);
        if (mc > MD) mc = MD;
        if (mc <= 0 || nc <= 0) return;
    }

    bf16* xbuf = (bf16*)d_ws;
    bf16* wbuf = xbuf + (size_t)mc * KD;

    for (int m0 = 0; m0 < MD; m0 += mc) {
        int mrows = (MD - m0 < mc) ? (MD - m0) : mc;   // multiple of 256
        int n8 = mrows * (KD / 8);
        cvt_kernel<<<(n8 + 255) / 256, 256, 0, stream>>>(x + (size_t)m0 * KD, xbuf, n8);
        for (int n0 = 0; n0 < ND; n0 += nc) {
            int nrows = (ND - n0 < nc) ? (ND - n0) : nc;  // multiple of 256
            int tt = nrows * (KD / 8);
            dequant_kernel<<<(tt + 255) / 256, 256, 0, stream>>>(wp, sc, wbuf, n0, nrows);
            int mt = mrows / 256, nt2 = nrows / 256;
            gemm256<<<mt * nt2, 512, 0, stream>>>(xbuf, wbuf, out + (size_t)m0 * ND, mt, nt2, n0);
        }
    }
}